// Round 9
// baseline (418.444 us; speedup 1.0000x reference)
//
#include <hip/hip_runtime.h>

#define BB 4
#define CC 64
#define HH 112
#define WW 112
#define MD 20
#define KD 41
#define S2 14426.950408f      // (1/TEMP) * log2(e): sims pre-scaled into exp2 domain
#define NPIX (BB*HH*WW)
#define NT 10                 // B quads per row (p = w + dyi in [0,160))
#define ROW2 (NT*2*2*64*8)    // in2s ushorts per (b,row): 20480
#define IN2S_BYTES ((size_t)BB*HH*ROW2*2)   // 18,350,080
#define NEG (-60000.0f)
#define NTILE (BB*HH*7)       // 3136 (b,h,wt) tiles

typedef _Float16 half8   __attribute__((ext_vector_type(8)));
typedef float    f32x4   __attribute__((ext_vector_type(4)));
typedef unsigned short ushort8 __attribute__((ext_vector_type(8)));

static __device__ __forceinline__ float fmax_f(float a, float b) { return a > b ? a : b; }
static __device__ __forceinline__ unsigned short f2h_bits(float x) {
    _Float16 h = (_Float16)x;
    return __builtin_bit_cast(unsigned short, h);
}
static __device__ __forceinline__ float h2f(unsigned short s) {
    return (float)__builtin_bit_cast(_Float16, s);
}
static __device__ __forceinline__ f32x4 vmax4(f32x4 a, f32x4 b) {
    f32x4 r;
    #pragma unroll
    for (int k = 0; k < 4; ++k) r[k] = a[k] > b[k] ? a[k] : b[k];
    return r;
}
static __device__ __forceinline__ f32x4 vexp4(f32x4 d) {
    f32x4 r;
    #pragma unroll
    for (int k = 0; k < 4; ++k) r[k] = __builtin_amdgcn_exp2f(d[k]);
    return r;
}
static __device__ __forceinline__ f32x4 mfma16(half8 a, half8 b, f32x4 c) {
    return __builtin_amdgcn_mfma_f32_16x16x32_f16(a, b, c, 0, 0, 0);
}

// ---- pack: one 64-thread block per (b,h,tau) unit. No LDS. Lane owns one
// column x 16 channels; column norm via q-butterfly. Also zeroes the merge
// counters (visible to corr via kernel boundary). ----
__global__ __launch_bounds__(64) void pack_kernel(const float* __restrict__ in2,
                                                  unsigned short* __restrict__ in2s,
                                                  unsigned int* __restrict__ cnt) {
    int wid = blockIdx.x;               // [0, 4480)
    int lane = threadIdx.x;
    if (wid < (NTILE + 63)/64) {        // 49 blocks zero 3136 counters
        int i = wid*64 + lane;
        if (i < NTILE) cnt[i] = 0u;
    }
    int tau = wid % NT;
    int bh  = wid / NT;
    int b = bh / HH, h = bh % HH;
    int n = lane & 15, q = lane >> 4;
    int col = 16*tau + n - MD;
    bool ok = (col >= 0 && col < WW);
    const float* src = in2 + ((size_t)(b*CC)*HH + h)*WW + (ok ? col : 0);

    float x[16];
    float ss = 0.f;
    #pragma unroll
    for (int ks = 0; ks < 2; ++ks)
        #pragma unroll
        for (int j = 0; j < 8; ++j) {
            float v = ok ? src[(size_t)(32*ks + 8*q + j)*(HH*WW)] : 0.f;
            x[ks*8 + j] = v;
            ss += v*v;
        }
    ss += __shfl_xor(ss, 16);           // q-butterfly: full 64-ch column norm
    ss += __shfl_xor(ss, 32);
    float iv = 1.0f / fmax_f(__builtin_sqrtf(ss), 1e-12f);

    unsigned short* base = in2s + (size_t)(b*HH + h)*ROW2;
    #pragma unroll
    for (int ks = 0; ks < 2; ++ks) {
        ushort8 hb, lb;
        #pragma unroll
        for (int j = 0; j < 8; ++j) {
            float v = x[ks*8 + j] * iv;
            unsigned short vh = f2h_bits(v);
            hb[j] = vh;
            lb[j] = f2h_bits((v - h2f(vh)) * 4096.0f);
        }
        *(ushort8*)(base + (size_t)((tau*4 + ks*2 + 0)*64 + lane)*8) = hb;
        *(ushort8*)(base + (size_t)((tau*4 + ks*2 + 1)*64 + lane)*8) = lb;
    }
}

// ---- corr: round-6 structure (7-wave blocks, dx-split x3, XCD slab pinning)
// + last-arrival merge: the 3rd g-wave to finish a (b,h,wt) tile merges the
// partials and writes flow. No separate merge kernel. ----
__global__ __launch_bounds__(448) void corr_kernel(const float* __restrict__ in1,
                                                   const unsigned short* __restrict__ in2s,
                                                   float* __restrict__ part,
                                                   unsigned int* __restrict__ cnt,
                                                   float* __restrict__ out) {
    int gid = blockIdx.x;               // [0, 1344)
    int xcd  = gid & 7;                 // XCD slab pinning
    int slot = gid >> 3;                // [0, 168)
    int hloc = slot % 56;
    int g    = slot / 56;               // dx group [0,3)
    int b    = xcd >> 1;
    int h    = (xcd & 1)*56 + hloc;
    int wt   = threadIdx.x >> 6;        // wave = w-tile, 0..6
    int lane = threadIdx.x & 63;
    int n = lane & 15, q = lane >> 4;
    int m0 = 4*q;
    int wA = wt*16 + n;

    // ---- in1 channels; inv1 via q-butterfly; split A fragments ----
    const float* a_src = in1 + ((size_t)(b*CC)*HH + h)*WW + wA;
    float x[16];
    float ss = 0.f;
    #pragma unroll
    for (int ks = 0; ks < 2; ++ks)
        #pragma unroll
        for (int j = 0; j < 8; ++j) {
            float v = a_src[(size_t)(32*ks + 8*q + j)*(HH*WW)];
            x[ks*8 + j] = v;
            ss += v*v;
        }
    ss += __shfl_xor(ss, 16);
    ss += __shfl_xor(ss, 32);
    float i1 = 1.0f / fmax_f(__builtin_sqrtf(ss), 1e-12f);
    half8 aH[2], aL[2];
    #pragma unroll
    for (int ks = 0; ks < 2; ++ks)
        #pragma unroll
        for (int j = 0; j < 8; ++j) {
            float v = x[ks*8 + j] * i1;
            _Float16 vh = (_Float16)v;
            aH[ks][j] = vh;
            aL[ks][j] = (_Float16)((v - (float)vh) * 4096.0f);
        }

    // ---- per-r constants (dyi = 16*oi + n - m) ----
    f32x4 NM20; bool v0b[4], v2b[4], v3b[4];
    #pragma unroll
    for (int r = 0; r < 4; ++r) {
        int nm = n - (m0 + r);
        NM20[r] = (float)(nm - 20);
        v0b[r] = (nm >= 0);
        v2b[r] = (nm <= 8);
        v3b[r] = (nm <= -8);
    }

    f32x4 SM = {NEG,NEG,NEG,NEG}, SL = {0.f,0.f,0.f,0.f};
    f32x4 SSX = {0.f,0.f,0.f,0.f}, SSY = {0.f,0.f,0.f,0.f};

    int glo = g*14;
    int ghi = glo + 14 < KD ? glo + 14 : KD;    // 14,14,13
    int lo = glo > (MD - h) ? glo : (MD - h);
    int hi0 = HH + MD - h;
    int hi = ghi < hi0 ? ghi : hi0;
    if (hi < lo) { lo = ghi; hi = ghi; }

    for (int dxi = lo; dxi < hi; ++dxi) {
        const unsigned short* rb = in2s + (size_t)(b*HH + (h + dxi - MD))*ROW2;
        half8 bf[4][4];
        #pragma unroll
        for (int oi = 0; oi < 4; ++oi) {
            const half8* fp = (const half8*)(rb + (size_t)((wt + oi)*4*64 + lane)*8);
            bf[oi][0] = fp[0];    // ks0 hi
            bf[oi][1] = fp[64];   // ks0 lo
            bf[oi][2] = fp[128];  // ks1 hi
            bf[oi][3] = fp[192];  // ks1 lo
        }
        f32x4 sv[4];
        #pragma unroll
        for (int oi = 0; oi < 4; ++oi) {
            f32x4 a0 = {0.f,0.f,0.f,0.f}, a1 = {0.f,0.f,0.f,0.f};
            a0 = mfma16(aH[0], bf[oi][0], a0);
            a1 = mfma16(aH[0], bf[oi][1], a1);
            a1 = mfma16(aL[0], bf[oi][0], a1);
            a0 = mfma16(aH[1], bf[oi][2], a0);
            a1 = mfma16(aH[1], bf[oi][3], a1);
            a1 = mfma16(aL[1], bf[oi][2], a1);
            sv[oi] = a0*S2 + a1*(S2/4096.0f);
        }
        f32x4 V0, V1 = sv[1], V2, V3;
        #pragma unroll
        for (int r = 0; r < 4; ++r) {
            V0[r] = v0b[r] ? sv[0][r] : NEG;
            V2[r] = v2b[r] ? sv[2][r] : NEG;
            V3[r] = v3b[r] ? sv[3][r] : NEG;
        }
        f32x4 MN = vmax4(vmax4(SM, V0), vmax4(V1, vmax4(V2, V3)));
        f32x4 ER = vexp4(SM - MN);
        f32x4 E0 = vexp4(V0 - MN);
        f32x4 E1 = vexp4(V1 - MN);
        f32x4 E2 = vexp4(V2 - MN);
        f32x4 E3 = vexp4(V3 - MN);
        f32x4 SUM = (E0 + E1) + (E2 + E3);
        f32x4 TT  = E1 + E2*2.0f + E3*3.0f;
        float dxf = (float)(dxi - MD);
        SL  = SL *ER + SUM;
        SSX = SSX*ER + SUM*dxf;
        SSY = SSY*ER + (TT*16.0f + NM20*SUM);
        SM  = MN;
    }

    // out-of-image dx rows in this group: all 41 sims exactly 0 (scaled 0)
    int miss = (lo - glo) + (ghi - hi);
    if (miss > 0) {
        float sdx = 0.f;
        for (int d = glo; d < lo; ++d)  sdx += (float)(d - MD);
        for (int d = hi; d < ghi; ++d)  sdx += (float)(d - MD);
        float cntf = (float)miss * (float)KD;
        f32x4 Z = {0.f,0.f,0.f,0.f};
        f32x4 MN = vmax4(SM, Z);
        f32x4 ER = vexp4(SM - MN);
        f32x4 E0 = vexp4(Z  - MN);
        SL  = SL *ER + E0*cntf;
        SSX = SSX*ER + E0*((float)KD*sdx);
        SSY = SSY*ER;
        SM  = MN;
    }

    // butterfly merge across the 16 n-lanes
    #pragma unroll
    for (int off = 1; off < 16; off <<= 1) {
        f32x4 M2, L2, X2, Y2;
        #pragma unroll
        for (int k = 0; k < 4; ++k) {
            M2[k] = __shfl_xor(SM[k],  off);
            L2[k] = __shfl_xor(SL[k],  off);
            X2[k] = __shfl_xor(SSX[k], off);
            Y2[k] = __shfl_xor(SSY[k], off);
        }
        f32x4 MN = vmax4(SM, M2);
        f32x4 EA = vexp4(SM - MN);
        f32x4 EB = vexp4(M2 - MN);
        SL  = SL *EA + L2*EB;
        SSX = SSX*EA + X2*EB;
        SSY = SSY*EA + Y2*EB;
        SM  = MN;
    }

    // ---- write this group's partial for the tile ----
    int tile = (b*HH + h)*7 + wt;
    if (n == 0) {
        #pragma unroll
        for (int r = 0; r < 4; ++r) {
            int w = wt*16 + m0 + r;
            int pix = (b*HH + h)*WW + w;
            f32x4 rec = {SM[r], SL[r], SSX[r], SSY[r]};
            *(f32x4*)&part[(size_t)(g*NPIX + pix)*4] = rec;
        }
    }

    // ---- last-arrival merge: 3rd g-wave for this tile merges and emits flow ----
    __threadfence();                               // release partial stores
    unsigned int old = 0u;
    if (lane == 0) old = atomicAdd(&cnt[tile], 1u);
    old = __shfl(old, 0);
    if (old == 2u) {
        __threadfence();                           // acquire other partials
        if (lane < 16) {
            int w = wt*16 + lane;
            int pix = (b*HH + h)*WW + w;
            f32x4 p0 = *(const f32x4*)&part[(size_t)(0*NPIX + pix)*4];
            f32x4 p1 = *(const f32x4*)&part[(size_t)(1*NPIX + pix)*4];
            f32x4 p2 = *(const f32x4*)&part[(size_t)(2*NPIX + pix)*4];
            float M = fmax_f(fmax_f(p0[0], p1[0]), p2[0]);
            float e0 = __builtin_amdgcn_exp2f(p0[0] - M);
            float e1 = __builtin_amdgcn_exp2f(p1[0] - M);
            float e2 = __builtin_amdgcn_exp2f(p2[0] - M);
            float L  = p0[1]*e0 + p1[1]*e1 + p2[1]*e2;
            float SX = p0[2]*e0 + p1[2]*e1 + p2[2]*e2;
            float SY = p0[3]*e0 + p1[3]*e1 + p2[3]*e2;
            out[((b*2 + 0)*HH + h)*WW + w] = SX / L;
            out[((b*2 + 1)*HH + h)*WW + w] = SY / L;
        }
    }
}

extern "C" void kernel_launch(void* const* d_in, const int* in_sizes, int n_in,
                              void* d_out, int out_size, void* d_ws, size_t ws_size,
                              hipStream_t stream) {
    const float* in1 = (const float*)d_in[0];
    const float* in2 = (const float*)d_in[1];
    float* out = (float*)d_out;
    unsigned short* in2s = (unsigned short*)d_ws;
    float* part = (float*)((char*)d_ws + IN2S_BYTES);         // [3][NPIX][4]
    unsigned int* cnt = (unsigned int*)(part + (size_t)3*NPIX*4);  // [3136]

    pack_kernel<<<BB*HH*NT, 64, 0, stream>>>(in2, in2s, cnt);
    corr_kernel<<<1344, 448, 0, stream>>>(in1, in2s, part, cnt, out);
}

// Round 10
// 154.994 us; speedup vs baseline: 2.6997x; 2.6997x over previous
//
#include <hip/hip_runtime.h>

#define BB 4
#define CC 64
#define HH 112
#define WW 112
#define MD 20
#define KD 41
#define S2 14426.950408f      // (1/TEMP) * log2(e): sims pre-scaled into exp2 domain
#define NPIX (BB*HH*WW)
#define NT 10                 // B quads per row (p = w + dyi in [0,160))
#define ROW2 (NT*2*2*64*8)    // in2s ushorts per (b,row): 20480
#define IN2S_BYTES ((size_t)BB*HH*ROW2*2)   // 18,350,080
#define NEG (-60000.0f)

typedef _Float16 half8   __attribute__((ext_vector_type(8)));
typedef float    f32x4   __attribute__((ext_vector_type(4)));
typedef unsigned short ushort8 __attribute__((ext_vector_type(8)));

static __device__ __forceinline__ float fmax_f(float a, float b) { return a > b ? a : b; }
static __device__ __forceinline__ unsigned short f2h_bits(float x) {
    _Float16 h = (_Float16)x;
    return __builtin_bit_cast(unsigned short, h);
}
static __device__ __forceinline__ float h2f(unsigned short s) {
    return (float)__builtin_bit_cast(_Float16, s);
}
static __device__ __forceinline__ f32x4 vmax4(f32x4 a, f32x4 b) {
    f32x4 r;
    #pragma unroll
    for (int k = 0; k < 4; ++k) r[k] = a[k] > b[k] ? a[k] : b[k];
    return r;
}
static __device__ __forceinline__ f32x4 vexp4(f32x4 d) {
    f32x4 r;
    #pragma unroll
    for (int k = 0; k < 4; ++k) r[k] = __builtin_amdgcn_exp2f(d[k]);
    return r;
}
static __device__ __forceinline__ f32x4 mfma16(half8 a, half8 b, f32x4 c) {
    return __builtin_amdgcn_mfma_f32_16x16x32_f16(a, b, c, 0, 0, 0);
}

// ---- pack: one 64-thread block per (b,h,tau) unit (best measured variant). ----
__global__ __launch_bounds__(64) void pack_kernel(const float* __restrict__ in2,
                                                  unsigned short* __restrict__ in2s) {
    int wid = blockIdx.x;               // [0, 4480)
    int lane = threadIdx.x;
    int tau = wid % NT;
    int bh  = wid / NT;
    int b = bh / HH, h = bh % HH;
    int n = lane & 15, q = lane >> 4;
    int col = 16*tau + n - MD;
    bool ok = (col >= 0 && col < WW);
    const float* src = in2 + ((size_t)(b*CC)*HH + h)*WW + (ok ? col : 0);

    float x[16];
    float ss = 0.f;
    #pragma unroll
    for (int ks = 0; ks < 2; ++ks)
        #pragma unroll
        for (int j = 0; j < 8; ++j) {
            float v = ok ? src[(size_t)(32*ks + 8*q + j)*(HH*WW)] : 0.f;
            x[ks*8 + j] = v;
            ss += v*v;
        }
    ss += __shfl_xor(ss, 16);           // q-butterfly: full 64-ch column norm
    ss += __shfl_xor(ss, 32);
    float iv = 1.0f / fmax_f(__builtin_sqrtf(ss), 1e-12f);

    unsigned short* base = in2s + (size_t)(b*HH + h)*ROW2;
    #pragma unroll
    for (int ks = 0; ks < 2; ++ks) {
        ushort8 hb, lb;
        #pragma unroll
        for (int j = 0; j < 8; ++j) {
            float v = x[ks*8 + j] * iv;
            unsigned short vh = f2h_bits(v);
            hb[j] = vh;
            lb[j] = f2h_bits((v - h2f(vh)) * 4096.0f);
        }
        *(ushort8*)(base + (size_t)((tau*4 + ks*2 + 0)*64 + lane)*8) = hb;
        *(ushort8*)(base + (size_t)((tau*4 + ks*2 + 1)*64 + lane)*8) = lb;
    }
}

// ---- templated tile-group worker: TN adjacent 16-pixel tiles starting at
// quad q0, sharing NQ B-quads per dx iteration. All compile-time constants. ----
template<int TN, int NQ>
static __device__ __forceinline__ void corr_tiles(int b, int h, int g, int q0, int lane,
                                                  const float* __restrict__ in1,
                                                  const unsigned short* __restrict__ in2s,
                                                  float* __restrict__ part) {
    int n = lane & 15, q = lane >> 4;
    int m0 = 4*q;

    // ---- A fragments per tile (fp16 split, inv-norm via q-butterfly) ----
    half8 aH[TN][2], aL[TN][2];
    #pragma unroll
    for (int t = 0; t < TN; ++t) {
        int wA = (q0 + t)*16 + n;
        const float* a_src = in1 + ((size_t)(b*CC)*HH + h)*WW + wA;
        float x[16], ss = 0.f;
        #pragma unroll
        for (int ks = 0; ks < 2; ++ks)
            #pragma unroll
            for (int j = 0; j < 8; ++j) {
                float v = a_src[(size_t)(32*ks + 8*q + j)*(HH*WW)];
                x[ks*8 + j] = v;
                ss += v*v;
            }
        ss += __shfl_xor(ss, 16);
        ss += __shfl_xor(ss, 32);
        float i1 = 1.0f / fmax_f(__builtin_sqrtf(ss), 1e-12f);
        #pragma unroll
        for (int ks = 0; ks < 2; ++ks)
            #pragma unroll
            for (int j = 0; j < 8; ++j) {
                float v = x[ks*8 + j] * i1;
                _Float16 vh = (_Float16)v;
                aH[t][ks][j] = vh;
                aL[t][ks][j] = (_Float16)((v - (float)vh) * 4096.0f);
            }
    }

    // ---- per-r constants (dyi = 16*oi + n - m), shared across tiles ----
    f32x4 NM20; bool v0b[4], v2b[4], v3b[4];
    #pragma unroll
    for (int r = 0; r < 4; ++r) {
        int nm = n - (m0 + r);
        NM20[r] = (float)(nm - 20);
        v0b[r] = (nm >= 0);
        v2b[r] = (nm <= 8);
        v3b[r] = (nm <= -8);
    }

    f32x4 SM[TN], SL[TN], SSX[TN], SSY[TN];
    #pragma unroll
    for (int t = 0; t < TN; ++t) {
        SM[t] = f32x4{NEG,NEG,NEG,NEG}; SL[t] = f32x4{0.f,0.f,0.f,0.f};
        SSX[t] = f32x4{0.f,0.f,0.f,0.f}; SSY[t] = f32x4{0.f,0.f,0.f,0.f};
    }

    int glo = g*14;
    int ghi = glo + 14 < KD ? glo + 14 : KD;    // 14,14,13
    int lo = glo > (MD - h) ? glo : (MD - h);
    int hi0 = HH + MD - h;
    int hi = ghi < hi0 ? ghi : hi0;
    if (hi < lo) { lo = ghi; hi = ghi; }

    for (int dxi = lo; dxi < hi; ++dxi) {
        const unsigned short* rb = in2s + (size_t)(b*HH + (h + dxi - MD))*ROW2
                                 + (size_t)q0*2048 + (size_t)lane*8;
        // shared B quads, batched loads
        half8 bq[NQ][4];
        #pragma unroll
        for (int j = 0; j < NQ; ++j) {
            const half8* fp = (const half8*)(rb + (size_t)j*2048);
            bq[j][0] = fp[0];     // ks0 hi
            bq[j][1] = fp[64];    // ks0 lo
            bq[j][2] = fp[128];   // ks1 hi
            bq[j][3] = fp[192];   // ks1 lo
        }
        float dxf = (float)(dxi - MD);
        #pragma unroll
        for (int t = 0; t < TN; ++t) {
            f32x4 sv[4];
            #pragma unroll
            for (int oi = 0; oi < 4; ++oi) {
                const half8* f = bq[t + oi];
                f32x4 a0 = {0.f,0.f,0.f,0.f}, a1 = {0.f,0.f,0.f,0.f};
                a0 = mfma16(aH[t][0], f[0], a0);
                a1 = mfma16(aH[t][0], f[1], a1);
                a1 = mfma16(aL[t][0], f[0], a1);
                a0 = mfma16(aH[t][1], f[2], a0);
                a1 = mfma16(aH[t][1], f[3], a1);
                a1 = mfma16(aL[t][1], f[2], a1);
                sv[oi] = a0*S2 + a1*(S2/4096.0f);
            }
            f32x4 V0, V1 = sv[1], V2, V3;
            #pragma unroll
            for (int r = 0; r < 4; ++r) {
                V0[r] = v0b[r] ? sv[0][r] : NEG;
                V2[r] = v2b[r] ? sv[2][r] : NEG;
                V3[r] = v3b[r] ? sv[3][r] : NEG;
            }
            f32x4 MN = vmax4(vmax4(SM[t], V0), vmax4(V1, vmax4(V2, V3)));
            f32x4 ER = vexp4(SM[t] - MN);
            f32x4 E0 = vexp4(V0 - MN);
            f32x4 E1 = vexp4(V1 - MN);
            f32x4 E2 = vexp4(V2 - MN);
            f32x4 E3 = vexp4(V3 - MN);
            f32x4 SUM = (E0 + E1) + (E2 + E3);
            f32x4 TT  = E1 + E2*2.0f + E3*3.0f;
            SL[t]  = SL[t] *ER + SUM;
            SSX[t] = SSX[t]*ER + SUM*dxf;
            SSY[t] = SSY[t]*ER + (TT*16.0f + NM20*SUM);
            SM[t]  = MN;
        }
    }

    // out-of-image dx rows: all 41 sims exactly 0 (scaled 0)
    int miss = (lo - glo) + (ghi - hi);
    if (miss > 0) {
        float sdx = 0.f;
        for (int d = glo; d < lo; ++d)  sdx += (float)(d - MD);
        for (int d = hi; d < ghi; ++d)  sdx += (float)(d - MD);
        float cntf = (float)miss * (float)KD;
        #pragma unroll
        for (int t = 0; t < TN; ++t) {
            f32x4 Z = {0.f,0.f,0.f,0.f};
            f32x4 MN = vmax4(SM[t], Z);
            f32x4 ER = vexp4(SM[t] - MN);
            f32x4 E0 = vexp4(Z - MN);
            SL[t]  = SL[t] *ER + E0*cntf;
            SSX[t] = SSX[t]*ER + E0*((float)KD*sdx);
            SSY[t] = SSY[t]*ER;
            SM[t]  = MN;
        }
    }

    // butterfly merge across the 16 n-lanes; write partials
    #pragma unroll
    for (int t = 0; t < TN; ++t) {
        #pragma unroll
        for (int off = 1; off < 16; off <<= 1) {
            f32x4 M2, L2, X2, Y2;
            #pragma unroll
            for (int k = 0; k < 4; ++k) {
                M2[k] = __shfl_xor(SM[t][k],  off);
                L2[k] = __shfl_xor(SL[t][k],  off);
                X2[k] = __shfl_xor(SSX[t][k], off);
                Y2[k] = __shfl_xor(SSY[t][k], off);
            }
            f32x4 MN = vmax4(SM[t], M2);
            f32x4 EA = vexp4(SM[t] - MN);
            f32x4 EB = vexp4(M2 - MN);
            SL[t]  = SL[t] *EA + L2*EB;
            SSX[t] = SSX[t]*EA + X2*EB;
            SSY[t] = SSY[t]*EA + Y2*EB;
            SM[t]  = MN;
        }
        if (n == 0) {
            #pragma unroll
            for (int r = 0; r < 4; ++r) {
                int w = (q0 + t)*16 + m0 + r;
                int pix = (b*HH + h)*WW + w;
                f32x4 rec = {SM[t][r], SL[t][r], SSX[t][r], SSY[t][r]};
                *(f32x4*)&part[(size_t)(g*NPIX + pix)*4] = rec;
            }
        }
    }
}

// ---- corr: block = (b,h,dxg), 4 waves: 3 tile-pairs + 1 singleton.
// Pairs share 5 B-quads across 32 pixels -> 1.6x less L1 traffic/pixel. ----
__global__ __launch_bounds__(256, 2) void corr_kernel(const float* __restrict__ in1,
                                                      const unsigned short* __restrict__ in2s,
                                                      float* __restrict__ part) {
    int gid = blockIdx.x;               // [0, 1344)
    int xcd  = gid & 7;                 // XCD slab pinning
    int slot = gid >> 3;                // [0, 168)
    int hloc = slot % 56;
    int g    = slot / 56;               // dx group [0,3)
    int b    = xcd >> 1;
    int h    = (xcd & 1)*56 + hloc;
    int u    = threadIdx.x >> 6;        // 0..3
    int lane = threadIdx.x & 63;

    if (u < 3) corr_tiles<2,5>(b, h, g, 2*u, lane, in1, in2s, part);
    else       corr_tiles<1,4>(b, h, g, 6,   lane, in1, in2s, part);
}

// ---- merge the 3 dx-group partials (scaled domain), emit flow ----
__global__ __launch_bounds__(256) void merge_kernel(const float* __restrict__ part,
                                                    float* __restrict__ out) {
    int idx = blockIdx.x*256 + threadIdx.x;
    if (idx >= NPIX) return;
    const float* p0 = &part[(size_t)idx*4];
    const float* p1 = &part[(size_t)(NPIX + idx)*4];
    const float* p2 = &part[(size_t)(2*NPIX + idx)*4];
    float M = fmax_f(fmax_f(p0[0], p1[0]), p2[0]);
    float e0 = __builtin_amdgcn_exp2f(p0[0] - M);
    float e1 = __builtin_amdgcn_exp2f(p1[0] - M);
    float e2 = __builtin_amdgcn_exp2f(p2[0] - M);
    float L  = p0[1]*e0 + p1[1]*e1 + p2[1]*e2;
    float SX = p0[2]*e0 + p1[2]*e1 + p2[2]*e2;
    float SY = p0[3]*e0 + p1[3]*e1 + p2[3]*e2;
    int b = idx / (HH*WW), rem = idx % (HH*WW);
    out[(b*2 + 0)*(HH*WW) + rem] = SX / L;
    out[(b*2 + 1)*(HH*WW) + rem] = SY / L;
}

extern "C" void kernel_launch(void* const* d_in, const int* in_sizes, int n_in,
                              void* d_out, int out_size, void* d_ws, size_t ws_size,
                              hipStream_t stream) {
    const float* in1 = (const float*)d_in[0];
    const float* in2 = (const float*)d_in[1];
    float* out = (float*)d_out;
    unsigned short* in2s = (unsigned short*)d_ws;
    float* part = (float*)((char*)d_ws + IN2S_BYTES);   // [3][NPIX][4]

    pack_kernel <<<BB*HH*NT, 64, 0, stream>>>(in2, in2s);
    corr_kernel <<<1344, 256, 0, stream>>>(in1, in2s, part);
    merge_kernel<<<(NPIX+255)/256, 256, 0, stream>>>(part, out);
}